// Round 10
// baseline (674.053 us; speedup 1.0000x reference)
//
#include <hip/hip_runtime.h>
#include <math.h>

#define BB 64
#define TT 1024
#define KK 128
#define START_TAG 126
#define STOP_TAG 127
#define NTH 128      // 2 waves; lane tid owns row j = tid (full 128-wide dot in-lane)
#define CS 32        // timesteps of raw feats staged per chunk (16 KB LDS x2)

typedef float v4f __attribute__((ext_vector_type(4)));

// Raw workgroup barrier WITHOUT the vmcnt(0) drain __syncthreads performs.
__device__ __forceinline__ void step_barrier() {
  asm volatile("s_waitcnt lgkmcnt(0)" ::: "memory");  // own LDS writes visible
  __builtin_amdgcn_s_barrier();
  asm volatile("" ::: "memory");                      // no hoisting reads above
}

__device__ __forceinline__ float vmax4(v4f v) {
  return fmaxf(fmaxf(v[0], v[1]), fmaxf(v[2], v[3]));
}
__device__ __forceinline__ v4f exp4(v4f v, float m) {
  v4f o;
  o[0] = __expf(v[0] - m); o[1] = __expf(v[1] - m);
  o[2] = __expf(v[2] - m); o[3] = __expf(v[3] - m);
  return o;
}

// Forward algorithm, log/exp-free inner chain, lag-1 normalization.
// Lane tid owns row j=tid: E_row = exp(T[j][:] - maxT_j) in 32 named v4f,
// each PINNED to a distinct 4-VGPR tuple via empty asm (rounds 7/9 showed the
// compiler dumps the 512B aggregate to scratch: VGPR=88 + 1MB WRITE_SIZE).
// In-loop pins force residency every iteration. amdgpu_waves_per_eu(1) makes
// the full register budget available. LDS canary distinguishes stale-binary
// infra failures (LDS_Block_Size must change vs rounds 7/9's 34304).
__global__ __launch_bounds__(NTH, 1) __attribute__((amdgpu_waves_per_eu(1)))
void crf_forward(
    const float* __restrict__ feats,   // [B,T,K]
    const int*   __restrict__ tags,    // [B,T]
    const int*   __restrict__ lens,    // [B]
    const float* __restrict__ trans,   // [K,K]
    float*       __restrict__ out_pb)  // [B]: forward_score - gold_score
{
  __shared__ __align__(16) float ebuf[2][KK];       // double-buffered e
  __shared__ float sbuf[2];                         // double-buffered divisor
  __shared__ __align__(16) float Fraw[2][CS * KK];  // 2 x 16 KB raw feats
  __shared__ float wsum[2];
  __shared__ float canary[256];                     // freshness canary (1 KB)

  const int tid = threadIdx.x;                      // 0..127 == owned row
  const int b   = blockIdx.x;
  const int L   = lens[b];
  const float* fb = feats + (size_t)b * TT * KK;

  if (tid == 0) canary[0] = (float)L;               // keep canary allocated

  // ---- E row in 32 named v4f registers: load+max, then exp in place ----
#define EGRPS(X) X(0) X(1) X(2) X(3) X(4) X(5) X(6) X(7)
#define DECLG(g) v4f E##g##0, E##g##1, E##g##2, E##g##3;
  EGRPS(DECLG)
  float mT = -INFINITY;
  {
    const v4f* tr = (const v4f*)(trans + (size_t)tid * KK);
#define LOADG(g)                                                        \
    E##g##0 = tr[4*g+0]; E##g##1 = tr[4*g+1];                           \
    E##g##2 = tr[4*g+2]; E##g##3 = tr[4*g+3];                           \
    mT = fmaxf(mT, fmaxf(fmaxf(vmax4(E##g##0), vmax4(E##g##1)),         \
                         fmaxf(vmax4(E##g##2), vmax4(E##g##3))));
    EGRPS(LOADG)
#define EXPG(g)                                                         \
    E##g##0 = exp4(E##g##0, mT); E##g##1 = exp4(E##g##1, mT);           \
    E##g##2 = exp4(E##g##2, mT); E##g##3 = exp4(E##g##3, mT);
    EGRPS(EXPG)
  }
  // pin each v4f to its own register tuple (defeats aggregation/scratch)
#define PING(g) asm volatile("" : "+v"(E##g##0), "+v"(E##g##1),         \
                                  "+v"(E##g##2), "+v"(E##g##3));
  EGRPS(PING)

  // ---- init: e0 = onehot(START), s0 = 1, M0 = feats[b,0,START] ----
  float ev = (tid == START_TAG) ? 1.0f : 0.0f;      // lane's own e_j
  ebuf[0][tid] = ev;
  if (tid == 0) sbuf[0] = 1.0f;
  float M = fb[START_TAG];                          // uniform across lanes

  // ---- prefetch chunk 0 raw feats into registers (8 x float4, coalesced) ----
  float4 pf[8];
  {
    const float4* s4 = (const float4*)fb;
    #pragma unroll
    for (int i = 0; i < 8; ++i) pf[i] = s4[i * NTH + tid];
  }

  // ---- chunked main recurrence ----
  int p = 0;
  for (int c = 0; c * CS < L; ++c) {
    // stage current chunk regs -> LDS (vmcnt wait lands here; pf loads were
    // issued a full chunk ago, so the wait is ~free after c=0)
    float4* Fb4 = (float4*)Fraw[c & 1];
    #pragma unroll
    for (int i = 0; i < 8; ++i) Fb4[i * NTH + tid] = pf[i];
    // issue prefetch for chunk c+1; stays outstanding across step barriers
    if ((c + 1) * CS < L) {
      const float4* s4 = (const float4*)(fb + (size_t)(c + 1) * CS * KK);
      #pragma unroll
      for (int i = 0; i < 8; ++i) pf[i] = s4[i * NTH + tid];
    }
    step_barrier();                                 // Fraw (+init at c=0) visible

    const float* Fc = Fraw[c & 1];
    const int t_end = (L < (c + 1) * CS) ? L : (c + 1) * CS;
    for (int t = (c == 0) ? 1 : c * CS; t < t_end; ++t) {
      EGRPS(PING)                                   // E stays in registers

      // off-chain factors first: stale divisor + raw feat
      const float sp = sbuf[p];
      const float Fr = Fc[(t & (CS - 1)) * KK + tid];
      float rr; asm("v_rcp_f32 %0, %1" : "=v"(rr) : "v"(sp));
      const float rF = __expf(Fr + mT) * rr;

      // full matvec: 32 uniform broadcast b128 reads, 64 pk_fma in-lane
      const v4f* eb = (const v4f*)ebuf[p];
      v4f a0 = {0.f,0.f,0.f,0.f}, a1 = a0, a2 = a0, a3 = a0;
#define DOTG(g)                                                         \
      a0 += eb[4*g+0] * E##g##0;                                        \
      a1 += eb[4*g+1] * E##g##1;                                        \
      a2 += eb[4*g+2] * E##g##2;                                        \
      a3 += eb[4*g+3] * E##g##3;
      EGRPS(DOTG)
      v4f av = (a0 + a1) + (a2 + a3);
      const float d = (av[0] + av[1]) + (av[2] + av[3]);

      ev = d * rF;
      ebuf[p ^ 1][tid] = ev;                        // conflict-free all-gather
      if (tid == START_TAG) sbuf[p ^ 1] = d;        // d_START = sum_k e_k
      M += __logf(sp);                              // off-chain, uniform
      p ^= 1;
      step_barrier();
    }
  }

  // ---- terminal: fwd = M + log(sum_j e_j) ----
  float sm = ev;
  #pragma unroll
  for (int m = 1; m < 64; m <<= 1) sm += __shfl_xor(sm, m, 64);
  if ((tid & 63) == 0) wsum[tid >> 6] = sm;
  step_barrier();
  const float fwd = M + __logf(wsum[0] + wsum[1]);
  step_barrier();                                   // protect wsum reuse

  // ---- gold score (trans/feats L2-hot; independent gathers) ----
  float g = 0.f;
  const int* tg = tags + b * TT;
  for (int t = tid; t < TT; t += NTH) {
    if (t < L)     g += fb[(size_t)t * KK + tg[t]];
    if (t < L - 1) g += trans[(size_t)tg[t + 1] * KK + tg[t]];
  }
  #pragma unroll
  for (int m = 1; m < 64; m <<= 1) g += __shfl_xor(g, m, 64);
  if ((tid & 63) == 0) wsum[tid >> 6] = g;
  step_barrier();
  if (tid == 0) {
    float res = fwd - (wsum[0] + wsum[1]);
    if (L < 0) res += canary[0];                    // never true; keeps canary
    out_pb[b] = res;
  }
}

__global__ void crf_mean(const float* __restrict__ pb, float* __restrict__ out) {
  int tid = threadIdx.x;  // 64 threads, one wave
  float v = pb[tid];
  #pragma unroll
  for (int m = 1; m < 64; m <<= 1) v += __shfl_xor(v, m, 64);
  if (tid == 0) out[0] = v * (1.0f / 64.0f);
}

extern "C" void kernel_launch(void* const* d_in, const int* in_sizes, int n_in,
                              void* d_out, int out_size, void* d_ws, size_t ws_size,
                              hipStream_t stream) {
  const float* feats = (const float*)d_in[0];
  const int*   tags  = (const int*)d_in[1];
  const int*   lens  = (const int*)d_in[2];
  const float* trans = (const float*)d_in[3];
  float* pb = (float*)d_ws;   // 64 floats of scratch
  crf_forward<<<BB, NTH, 0, stream>>>(feats, tags, lens, trans, pb);
  crf_mean<<<1, 64, 0, stream>>>(pb, (float*)d_out);
}

// Round 12
// 435.395 us; speedup vs baseline: 1.5481x; 1.5481x over previous
//
#include <hip/hip_runtime.h>
#include <math.h>

#define BB 64
#define TT 1024
#define KK 128
#define START_TAG 126
#define STOP_TAG 127
#define NTH 256      // 4 waves; q = tid&3 (32-col chunk), g = tid>>2 -> rows 2g,2g+1
#define CS 64        // timesteps of F staged per chunk (32 KB LDS)
#define EP 36        // padded stride (floats) per 32-float e-chunk -> disjoint banks

typedef float v2f __attribute__((ext_vector_type(2)));
typedef float v4f __attribute__((ext_vector_type(4)));

// Raw workgroup barrier WITHOUT the vmcnt(0) drain __syncthreads performs.
// Only LDS ordering is needed per step; feat prefetch stays in flight across
// the whole chunk. Cross-wave ebuf/sbuf exchange under this barrier is
// validated by rounds 7-10 (passed, absmax=0).
__device__ __forceinline__ void step_barrier() {
  asm volatile("s_waitcnt lgkmcnt(0)" ::: "memory");
  __builtin_amdgcn_s_barrier();
  asm volatile("" ::: "memory");
}

// Intra-quad reductions via DPP quad_perm; add tree (q0+q1)+(q2+q3).
__device__ __forceinline__ float quad_add(float x) {
  int y = __builtin_amdgcn_update_dpp(0, __float_as_int(x), 0xB1, 0xF, 0xF, true); // [1,0,3,2]
  x = x + __int_as_float(y);
  y = __builtin_amdgcn_update_dpp(0, __float_as_int(x), 0x4E, 0xF, 0xF, true);     // [2,3,0,1]
  return x + __int_as_float(y);
}
__device__ __forceinline__ float quad_max(float x) {
  int y = __builtin_amdgcn_update_dpp(0, __float_as_int(x), 0xB1, 0xF, 0xF, true);
  x = fmaxf(x, __int_as_float(y));
  y = __builtin_amdgcn_update_dpp(0, __float_as_int(x), 0x4E, 0xF, 0xF, true);
  return fmaxf(x, __int_as_float(y));
}

// Forward algorithm, log/exp-free inner chain, lag-1 normalization.
// Structure = round 1's measured-best (VGPR=132, no spill: 64 E floats/lane as
// v2f[16]x2 — the proven register budget; 128 floats/lane spills, rounds 2/7/9/10).
// Deltas vs round 1: raw barrier (no per-step vmcnt drain), q==0-only e' writes
// (round 1's 4-lane same-address ds_write measured 1.25M bank conflicts), dense
// Fbuf staging layout, no Tld (gold gathers from L2-hot trans), lag-1 divisor.
__global__ __launch_bounds__(NTH) void crf_forward(
    const float* __restrict__ feats,   // [B,T,K]
    const int*   __restrict__ tags,    // [B,T]
    const int*   __restrict__ lens,    // [B]
    const float* __restrict__ trans,   // [K,K]
    float*       __restrict__ out_pb)  // [B]: forward_score - gold_score
{
  __shared__ __align__(16) float ebuf[2][4 * EP];   // double-buffered e (padded)
  __shared__ float sbuf[2];                         // double-buffered divisor
  __shared__ __align__(16) float maxT_lds[KK];
  __shared__ __align__(16) float Fbuf[CS * KK];     // 32 KB: F = exp(feat+maxT)
  __shared__ float wsum[NTH / 64];

  const int tid = threadIdx.x;
  const int b   = blockIdx.x;
  const int q   = tid & 3;                          // 32-col chunk
  const int g   = tid >> 2;                         // 0..63
  const int r0  = 2 * g;                            // rows r0, r0+1
  const int L   = lens[b];
  const float* fb = feats + (size_t)b * TT * KK;

  // ---- E row-pair chunk from global (L2-hot after first dispatch) ----
  v2f Ea[16], Eb[16];
  float m0 = -INFINITY, m1 = -INFINITY;
  {
    const float* t0 = trans + (size_t)r0 * KK + q * 32;
    const float* t1 = t0 + KK;
    #pragma unroll
    for (int i = 0; i < 16; ++i) {
      Ea[i] = *(const v2f*)(t0 + 2 * i);
      Eb[i] = *(const v2f*)(t1 + 2 * i);
      m0 = fmaxf(m0, fmaxf(Ea[i][0], Ea[i][1]));
      m1 = fmaxf(m1, fmaxf(Eb[i][0], Eb[i][1]));
    }
  }
  m0 = quad_max(m0);
  m1 = quad_max(m1);
  #pragma unroll
  for (int i = 0; i < 16; ++i) {
    Ea[i][0] = __expf(Ea[i][0] - m0); Ea[i][1] = __expf(Ea[i][1] - m0);
    Eb[i][0] = __expf(Eb[i][0] - m1); Eb[i][1] = __expf(Eb[i][1] - m1);
  }
  if (q == 0) { maxT_lds[r0] = m0; maxT_lds[r0 + 1] = m1; }

  // ---- init: e0 = onehot(START) (padded layout), s0 = 1, M0 = feats[b,0,START] ----
  if (tid < KK)
    ebuf[0][(tid >> 5) * EP + (tid & 31)] = (tid == START_TAG) ? 1.0f : 0.0f;
  if (tid == 0) sbuf[0] = 1.0f;
  float M = fb[START_TAG];                          // uniform; wave 0's is used

  // ---- prefetch chunk 0 feats (8 x float4/lane, dense 16B stride) ----
  float4 pf[8];
  {
    const float4* s4 = (const float4*)fb;
    #pragma unroll
    for (int i = 0; i < 8; ++i) pf[i] = s4[i * NTH + tid];
  }

  step_barrier();                                   // maxT/ebuf/sbuf visible

  // conversion slice: flat elem (i*NTH+tid)*4+c has j = ((tid&31)*4+c) for all i
  const v4f mTv = *(const v4f*)(maxT_lds + (tid & 31) * 4);

  // ---- chunked main recurrence ----
  int p = 0;
  for (int c = 0; c * CS < L; ++c) {
    // convert prefetched feats -> F = exp(feat + maxT), dense conflict-free writes
    float4* Fb4 = (float4*)Fbuf;
    #pragma unroll
    for (int i = 0; i < 8; ++i) {
      float4 v = pf[i];
      float4 o;
      o.x = __expf(v.x + mTv[0]); o.y = __expf(v.y + mTv[1]);
      o.z = __expf(v.z + mTv[2]); o.w = __expf(v.w + mTv[3]);
      Fb4[i * NTH + tid] = o;
    }
    // prefetch chunk c+1; stays outstanding across all step barriers
    if ((c + 1) * CS < TT) {
      const float4* s4 = (const float4*)(fb + (size_t)(c + 1) * CS * KK);
      #pragma unroll
      for (int i = 0; i < 8; ++i) pf[i] = s4[i * NTH + tid];
    }
    step_barrier();                                 // Fbuf visible

    const int t_end = (L < (c + 1) * CS) ? L : (c + 1) * CS;
    for (int t = (c == 0) ? 1 : c * CS; t < t_end; ++t) {
      const float* er = ebuf[p];
      float* ew = ebuf[p ^ 1];
      // off-chain factors: stale divisor (exact: M += log(sp)), F pair
      const float sp = sbuf[p];
      const v2f Fv = *(const v2f*)(Fbuf + (t & (CS - 1)) * KK + r0);
      float rr; asm("v_rcp_f32 %0, %1" : "=v"(rr) : "v"(sp));
      const float rF0 = rr * Fv[0];
      const float rF1 = rr * Fv[1];

      // dot phase: 16 broadcast ds_read_b64 + 32 pk_fma (round-1 association)
      const v2f* e2 = (const v2f*)(er + q * EP);
      v2f a0 = {0.f,0.f}, a1 = {0.f,0.f}, a2 = {0.f,0.f}, a3 = {0.f,0.f};
      v2f b0 = {0.f,0.f}, b1 = {0.f,0.f}, b2 = {0.f,0.f}, b3 = {0.f,0.f};
      #pragma unroll
      for (int i = 0; i < 4; ++i) {
        v2f ea0 = e2[4 * i + 0], ea1 = e2[4 * i + 1];
        v2f ea2 = e2[4 * i + 2], ea3 = e2[4 * i + 3];
        a0 += ea0 * Ea[4 * i + 0];
        a1 += ea1 * Ea[4 * i + 1];
        a2 += ea2 * Ea[4 * i + 2];
        a3 += ea3 * Ea[4 * i + 3];
        b0 += ea0 * Eb[4 * i + 0];
        b1 += ea1 * Eb[4 * i + 1];
        b2 += ea2 * Eb[4 * i + 2];
        b3 += ea3 * Eb[4 * i + 3];
      }
      v2f as = (a0 + a1) + (a2 + a3);
      v2f bs = (b0 + b1) + (b2 + b3);
      float d0 = quad_add(as[0] + as[1]);           // full d_{r0} in all 4 lanes
      float d1 = quad_add(bs[0] + bs[1]);           // full d_{r0+1}

      v2f ev; ev[0] = d0 * rF0; ev[1] = d1 * rF1;
      if (q == 0)                                   // single writer per row pair
        *(v2f*)(ew + (r0 >> 5) * EP + (r0 & 31)) = ev;
      if (tid == 252) sbuf[p ^ 1] = d0;             // g=63,q=0: row 126 = START
      if (tid < 64) M += __logf(sp);                // off-chain, wave 0 only
      p ^= 1;
      step_barrier();
    }
  }

  // ---- terminal: fwd = M + log(sum_j e_j), wave 0 ----
  float fwd = 0.f;
  {
    const float* efin = ebuf[p];
    if (tid < 64) {
      float sm = efin[(tid >> 5) * EP + (tid & 31)]
               + efin[((tid + 64) >> 5) * EP + ((tid + 64) & 31)];
      #pragma unroll
      for (int m = 1; m < 64; m <<= 1) sm += __shfl_xor(sm, m, 64);
      fwd = M + __logf(sm);
    }
  }

  // ---- gold score (trans/feats L2-hot; independent gathers) ----
  float gg = 0.f;
  const int* tg = tags + b * TT;
  for (int t = tid; t < TT; t += NTH) {
    if (t < L)     gg += fb[(size_t)t * KK + tg[t]];
    if (t < L - 1) gg += trans[(size_t)tg[t + 1] * KK + tg[t]];
  }
  #pragma unroll
  for (int m = 1; m < 64; m <<= 1) gg += __shfl_xor(gg, m, 64);
  if ((tid & 63) == 0) wsum[tid >> 6] = gg;
  step_barrier();
  if (tid == 0) {
    float gold = 0.f;
    #pragma unroll
    for (int w = 0; w < NTH / 64; ++w) gold += wsum[w];
    out_pb[b] = fwd - gold;
  }
}

__global__ void crf_mean(const float* __restrict__ pb, float* __restrict__ out) {
  int tid = threadIdx.x;  // 64 threads, one wave
  float v = pb[tid];
  #pragma unroll
  for (int m = 1; m < 64; m <<= 1) v += __shfl_xor(v, m, 64);
  if (tid == 0) out[0] = v * (1.0f / 64.0f);
}

extern "C" void kernel_launch(void* const* d_in, const int* in_sizes, int n_in,
                              void* d_out, int out_size, void* d_ws, size_t ws_size,
                              hipStream_t stream) {
  const float* feats = (const float*)d_in[0];
  const int*   tags  = (const int*)d_in[1];
  const int*   lens  = (const int*)d_in[2];
  const float* trans = (const float*)d_in[3];
  float* pb = (float*)d_ws;   // 64 floats of scratch
  crf_forward<<<BB, NTH, 0, stream>>>(feats, tags, lens, trans, pb);
  crf_mean<<<1, 64, 0, stream>>>(pb, (float*)d_out);
}